// Round 1
// baseline (206.590 us; speedup 1.0000x reference)
//
#include <hip/hip_runtime.h>
#include <stdint.h>
#include <stddef.h>

typedef __attribute__((ext_vector_type(8))) __bf16 bf16x8;
typedef __attribute__((ext_vector_type(4))) float f32x4;
typedef __attribute__((ext_vector_type(4))) unsigned short us4;
typedef __attribute__((ext_vector_type(8))) unsigned short us8;

#define NC 8          // s-chunks per (b,h)
#define SCHUNK 512
#define SS 32         // s-subtile
#define NSUB 16       // SCHUNK/SS
#define KNW 40        // natural k tile row pitch (32 s + 8 pad) -> 80B rows, 2-way banks

__device__ __forceinline__ unsigned short f2bf(float x) {
    unsigned int u = __builtin_bit_cast(unsigned int, x);
    u += 0x7FFFu + ((u >> 16) & 1u);
    return (unsigned short)(u >> 16);
}

// ---------------- K1: q projection -> bf16 q[bh][t][ch] in ws ----------------
__global__ __launch_bounds__(128) void k_qproj(
    const float* __restrict__ tokens, const float* __restrict__ q_w,
    const float* __restrict__ q_b, unsigned short* __restrict__ ws_q)
{
    const int bid = blockIdx.x;            // t*32 + b
    const int t = bid >> 5, b = bid & 31;
    const int d = threadIdx.x;
    __shared__ float tok[128];
    tok[d] = tokens[(size_t)bid * 128 + d];
    __syncthreads();
    #pragma unroll
    for (int i = 0; i < 4; ++i) {
        const int c = d + 128 * i;
        const float* wr = q_w + (size_t)c * 128;
        float acc = q_b[c];
        #pragma unroll 8
        for (int k = 0; k < 128; k += 4) {
            const float4 w4 = *(const float4*)(wr + k);
            acc += tok[k] * w4.x + tok[k+1] * w4.y + tok[k+2] * w4.z + tok[k+3] * w4.w;
        }
        const int h = c >> 8, cc = c & 255;
        ws_q[(size_t)((b * 2 + h) * 64 + t) * 256 + cc] = f2bf(acc);
    }
}

// ---------------- K2: fused QK^T -> S (out) -> exp -> partial AV ----------------
// grid: 64 bh * NC chunks ; block: 256 threads (4 waves)
__global__ __launch_bounds__(256, 2) void k_attn(
    const float* __restrict__ feat, const unsigned short* __restrict__ ws_q,
    float* __restrict__ attn_g,            // d_out + 262144
    float* __restrict__ part, float* __restrict__ zbuf)
{
    const int bh = blockIdx.x >> 3;
    const int nc = blockIdx.x & 7;
    const int b = bh >> 1, h = bh & 1;
    const int tid = threadIdx.x;
    const int lane = tid & 63;
    const int w = tid >> 6;                // wave id 0..3
    const int l15 = lane & 15, g = lane >> 4;

    __shared__ unsigned short q_lds[64 * 256];   // 32KB, swizzled [t][c]
    __shared__ unsigned short kT[SS * 256];      // 16KB, swizzled [s][c]
    __shared__ unsigned short knat[256 * KNW];   // 20KB, [c][s] pad
    __shared__ unsigned short P[64 * KNW];       // 5KB,  [t][s] pad

    // ---- stage q tile (global bf16 -> LDS swizzled) ----
    {
        const unsigned short* src = ws_q + (size_t)bh * 64 * 256;
        const int c8 = (tid & 31) * 8;
        #pragma unroll
        for (int p = 0; p < 8; ++p) {
            const int t = (tid >> 5) + p * 8;
            us8 v = *(const us8*)(src + (size_t)t * 256 + c8);
            *(us8*)&q_lds[t * 256 + (c8 ^ ((t & 15) << 3))] = v;
        }
    }

    f32x4 acc[4][4];
    #pragma unroll
    for (int i = 0; i < 4; ++i)
        #pragma unroll
        for (int j = 0; j < 4; ++j) { acc[i][j][0]=0.f; acc[i][j][1]=0.f; acc[i][j][2]=0.f; acc[i][j][3]=0.f; }
    float zp[4] = {0.f, 0.f, 0.f, 0.f};

    const float* fb = feat + ((size_t)b * 512 + (size_t)h * 256) * 4096;
    const int sw_base = nc * SCHUNK;
    const int t0 = w * 16;
    const int trow = t0 + l15;

    for (int ss = 0; ss < NSUB; ++ss) {
        const int sw = sw_base + ss * SS;
        __syncthreads();
        // ---- stage features subtile [256 c][32 s]: natural + transposed ----
        {
            const int s4 = (tid & 7) * 4;
            const int c0 = tid >> 3;
            #pragma unroll
            for (int p = 0; p < 8; ++p) {
                const int c = c0 + p * 32;
                const float4 f4 = *(const float4*)(fb + (size_t)c * 4096 + sw + s4);
                const unsigned short b0 = f2bf(f4.x), b1 = f2bf(f4.y),
                                     b2 = f2bf(f4.z), b3 = f2bf(f4.w);
                us4 v; v[0] = b0; v[1] = b1; v[2] = b2; v[3] = b3;
                *(us4*)&knat[c * KNW + s4] = v;
                kT[(s4+0) * 256 + (c ^ (((s4+0) & 15) << 3))] = b0;
                kT[(s4+1) * 256 + (c ^ (((s4+1) & 15) << 3))] = b1;
                kT[(s4+2) * 256 + (c ^ (((s4+2) & 15) << 3))] = b2;
                kT[(s4+3) * 256 + (c ^ (((s4+3) & 15) << 3))] = b3;
            }
        }
        __syncthreads();
        // ---- S-GEMM: wave w owns t rows [16w,16w+16), all 32 s ----
        bf16x8 afr[8];
        #pragma unroll
        for (int kk = 0; kk < 8; ++kk) {
            const int cc = kk * 32 + g * 8;
            afr[kk] = *(bf16x8*)&q_lds[trow * 256 + (cc ^ (l15 << 3))];
        }
        #pragma unroll
        for (int nt = 0; nt < 2; ++nt) {
            const int s_n = nt * 16 + l15;       // B-frag col (s)
            f32x4 d; d[0]=0.f; d[1]=0.f; d[2]=0.f; d[3]=0.f;
            #pragma unroll
            for (int kk = 0; kk < 8; ++kk) {
                const int cc = kk * 32 + g * 8;
                bf16x8 bfr = *(bf16x8*)&kT[s_n * 256 + (cc ^ (l15 << 3))];
                d = __builtin_amdgcn_mfma_f32_16x16x32_bf16(afr[kk], bfr, d, 0, 0, 0);
            }
            #pragma unroll
            for (int r = 0; r < 4; ++r) {
                const int t = t0 + g * 4 + r;
                const float sv = d[r] * 0.0625f;
                attn_g[((size_t)bh * 64 + t) * 4096 + sw + nt * 16 + l15] = sv;
                const float p = __expf(sv);
                zp[r] += p;
                P[t * KNW + nt * 16 + l15] = f2bf(p);
            }
        }
        __syncthreads();
        // ---- AV-GEMM: wave w owns c cols [64w,64w+64), all 64 t, K = 32 s ----
        #pragma unroll
        for (int tt = 0; tt < 4; ++tt) {
            const bf16x8 pa = *(bf16x8*)&P[(tt * 16 + l15) * KNW + g * 8];
            #pragma unroll
            for (int ct = 0; ct < 4; ++ct) {
                const bf16x8 kb = *(bf16x8*)&knat[(w * 64 + ct * 16 + l15) * KNW + g * 8];
                acc[tt][ct] = __builtin_amdgcn_mfma_f32_16x16x32_bf16(pa, kb, acc[tt][ct], 0, 0, 0);
            }
        }
    }

    // ---- epilogue: write AV partials + z partials ----
    const size_t pbase = (size_t)(bh * NC + nc) * 64 * 256;
    #pragma unroll
    for (int tt = 0; tt < 4; ++tt)
        #pragma unroll
        for (int ct = 0; ct < 4; ++ct)
            #pragma unroll
            for (int r = 0; r < 4; ++r)
                part[pbase + (size_t)(tt * 16 + g * 4 + r) * 256 + w * 64 + ct * 16 + l15] = acc[tt][ct][r];
    #pragma unroll
    for (int r = 0; r < 4; ++r) {
        float z = zp[r];
        z += __shfl_xor(z, 1); z += __shfl_xor(z, 2);
        z += __shfl_xor(z, 4); z += __shfl_xor(z, 8);
        if (l15 == 0) zbuf[(size_t)(bh * NC + nc) * 64 + w * 16 + g * 4 + r] = z;
    }
}

// ---------------- K3: combine partials, proj, residual, LayerNorm ----------------
__global__ __launch_bounds__(128) void k_post(
    const float* __restrict__ tokens, const float* __restrict__ proj_w,
    const float* __restrict__ proj_b, const float* __restrict__ ln_w,
    const float* __restrict__ ln_b, const float* __restrict__ part,
    const float* __restrict__ zbuf, float* __restrict__ out_tok)
{
    const int bid = blockIdx.x;            // t*32 + b
    const int t = bid >> 5, b = bid & 31;
    const int d = threadIdx.x;
    __shared__ float av[512];
    __shared__ float Zs[2];
    __shared__ float rs[2][2];

    #pragma unroll
    for (int i = 0; i < 4; ++i) {
        const int c = d + 128 * i;
        const int h = c >> 8, cc = c & 255;
        const int bh = b * 2 + h;
        float s = 0.f;
        #pragma unroll
        for (int nc = 0; nc < NC; ++nc)
            s += part[((size_t)(bh * NC + nc) * 64 + t) * 256 + cc];
        av[c] = s;
    }
    if (d < 2) {
        const int bh = b * 2 + d;
        float z = 0.f;
        for (int nc = 0; nc < NC; ++nc) z += zbuf[(size_t)(bh * NC + nc) * 64 + t];
        Zs[d] = z;
    }
    __syncthreads();
    const float rz0 = 1.f / Zs[0], rz1 = 1.f / Zs[1];
    #pragma unroll
    for (int i = 0; i < 4; ++i) {
        const int c = d + 128 * i;
        av[c] *= (c < 256) ? rz0 : rz1;
    }
    __syncthreads();

    float acc = proj_b[d];
    const float* wr = proj_w + (size_t)d * 512;
    #pragma unroll 8
    for (int c = 0; c < 512; c += 4) {
        const float4 w4 = *(const float4*)(wr + c);
        acc += av[c] * w4.x + av[c+1] * w4.y + av[c+2] * w4.z + av[c+3] * w4.w;
    }
    const float r = tokens[(size_t)bid * 128 + d] + acc;

    float s1 = r, s2 = r * r;
    #pragma unroll
    for (int o = 1; o < 64; o <<= 1) { s1 += __shfl_xor(s1, o); s2 += __shfl_xor(s2, o); }
    if ((d & 63) == 0) { rs[0][d >> 6] = s1; rs[1][d >> 6] = s2; }
    __syncthreads();
    const float mean = (rs[0][0] + rs[0][1]) * (1.f / 128.f);
    const float ex2  = (rs[1][0] + rs[1][1]) * (1.f / 128.f);
    const float var = ex2 - mean * mean;
    out_tok[(size_t)bid * 128 + d] = (r - mean) * rsqrtf(var + 1e-5f) * ln_w[d] + ln_b[d];
}

extern "C" void kernel_launch(void* const* d_in, const int* in_sizes, int n_in,
                              void* d_out, int out_size, void* d_ws, size_t ws_size,
                              hipStream_t stream) {
    const float* features = (const float*)d_in[0];
    const float* tokens   = (const float*)d_in[1];
    const float* q_w      = (const float*)d_in[2];
    const float* q_b      = (const float*)d_in[3];
    const float* proj_w   = (const float*)d_in[4];
    const float* proj_b   = (const float*)d_in[5];
    const float* ln_w     = (const float*)d_in[6];
    const float* ln_b     = (const float*)d_in[7];

    float* out = (float*)d_out;
    float* out_attn = out + (size_t)64 * 32 * 128;       // tok first, then attn

    unsigned short* ws_q = (unsigned short*)d_ws;        // 2 MB
    float* part = (float*)((char*)d_ws + (size_t)2 * 1024 * 1024);   // 33.6 MB
    float* zbuf = part + (size_t)64 * NC * 64 * 256;     // 128 KB

    k_qproj<<<2048, 128, 0, stream>>>(tokens, q_w, q_b, ws_q);
    k_attn<<<64 * NC, 256, 0, stream>>>(features, ws_q, out_attn, part, zbuf);
    k_post<<<2048, 128, 0, stream>>>(tokens, proj_w, proj_b, ln_w, ln_b, part, zbuf, out);
}

// Round 2
// 138.012 us; speedup vs baseline: 1.4969x; 1.4969x over previous
//
#include <hip/hip_runtime.h>
#include <stdint.h>
#include <stddef.h>

typedef __attribute__((ext_vector_type(8))) __bf16 bf16x8;
typedef __attribute__((ext_vector_type(4))) __bf16 bf16x4;
typedef __attribute__((ext_vector_type(4))) float f32x4;

#define NC 8          // s-chunks per (b,h)
#define SCHUNK 512
#define SS 32         // s-subtile
#define NSUB 16       // SCHUNK/SS
#define KNW 40        // natural k tile row pitch (32 s + 8 pad)

// ---------------- K1: q projection -> bf16 q[bh][t][ch] in ws ----------------
// grid 512: t = bid>>3, 4 consecutive b per block; q_w row reused x4
__global__ __launch_bounds__(128) void k_qproj(
    const float* __restrict__ tokens, const float* __restrict__ q_w,
    const float* __restrict__ q_b, __bf16* __restrict__ ws_q)
{
    const int t = blockIdx.x >> 3;
    const int b0 = (blockIdx.x & 7) * 4;
    const int d = threadIdx.x;
    __shared__ float tok[4][128];
    #pragma unroll
    for (int j = 0; j < 4; ++j)
        tok[j][d] = tokens[((size_t)t * 32 + b0 + j) * 128 + d];
    __syncthreads();
    #pragma unroll
    for (int i = 0; i < 4; ++i) {
        const int c = d + 128 * i;
        const float* wr = q_w + (size_t)c * 128;
        const float qb = q_b[c];
        float acc[4] = {qb, qb, qb, qb};
        #pragma unroll 4
        for (int k = 0; k < 128; k += 4) {
            const float4 w4 = *(const float4*)(wr + k);
            #pragma unroll
            for (int j = 0; j < 4; ++j) {
                const float4 t4 = *(const float4*)&tok[j][k];
                acc[j] += t4.x * w4.x + t4.y * w4.y + t4.z * w4.z + t4.w * w4.w;
            }
        }
        const int h = c >> 8, cc = c & 255;
        #pragma unroll
        for (int j = 0; j < 4; ++j)
            ws_q[(size_t)(((b0 + j) * 2 + h) * 64 + t) * 256 + cc] = (__bf16)acc[j];
    }
}

// ---------------- K2: fused QK^T -> S (out) -> exp -> partial AV ----------------
// grid: 64 bh * NC chunks ; block: 256 threads (4 waves)
__global__ __launch_bounds__(256, 2) void k_attn(
    const float* __restrict__ feat, const __bf16* __restrict__ ws_q,
    float* __restrict__ attn_g, float* __restrict__ part, float* __restrict__ zbuf)
{
    const int bh = blockIdx.x >> 3;
    const int nc = blockIdx.x & 7;
    const int b = bh >> 1, h = bh & 1;
    const int tid = threadIdx.x;
    const int lane = tid & 63;
    const int w = tid >> 6;                // wave id 0..3
    const int l15 = lane & 15, g = lane >> 4;
    const int t0 = w * 16;

    __shared__ __bf16 kT[SS * 256];        // 16KB, swizzled [s][c]
    __shared__ __bf16 knat[256 * KNW];     // 20KB, [c][s] pad
    __shared__ __bf16 P[64 * KNW];         // 5KB,  [t][s] pad (wave-private rows)

    // ---- q fragments: once, straight from global (L2-hot, 32KB/bh) ----
    bf16x8 afr[8];
    {
        const __bf16* qb = ws_q + ((size_t)bh * 64 + t0 + l15) * 256 + g * 8;
        #pragma unroll
        for (int kk = 0; kk < 8; ++kk)
            afr[kk] = *(const bf16x8*)(qb + kk * 32);
    }

    f32x4 acc[16];
    #pragma unroll
    for (int i = 0; i < 16; ++i) { acc[i][0]=0.f; acc[i][1]=0.f; acc[i][2]=0.f; acc[i][3]=0.f; }
    float zp[4] = {0.f, 0.f, 0.f, 0.f};

    const float* fb = feat + ((size_t)b * 512 + (size_t)h * 256) * 4096;
    const int sw_base = nc * SCHUNK;
    const int s4 = (tid & 7) * 4;
    const int c0 = tid >> 3;
    const float* fptr = fb + (size_t)c0 * 4096 + sw_base + s4;

    // prefetch subtile 0 into registers
    float4 f4[8];
    #pragma unroll
    for (int p = 0; p < 8; ++p)
        f4[p] = *(const float4*)(fptr + (size_t)p * 32 * 4096);

    #pragma unroll 1
    for (int ss = 0; ss < NSUB; ++ss) {
        __syncthreads();               // previous compute done reading kT/knat
        // ---- stage current subtile from regs: natural + transposed ----
        #pragma unroll
        for (int p = 0; p < 8; ++p) {
            const int c = c0 + p * 32;
            bf16x4 nb;
            nb[0] = (__bf16)f4[p].x; nb[1] = (__bf16)f4[p].y;
            nb[2] = (__bf16)f4[p].z; nb[3] = (__bf16)f4[p].w;
            *(bf16x4*)&knat[c * KNW + s4] = nb;
            kT[(s4+0) * 256 + (c ^ (((s4+0) & 15) << 3))] = nb[0];
            kT[(s4+1) * 256 + (c ^ (((s4+1) & 15) << 3))] = nb[1];
            kT[(s4+2) * 256 + (c ^ (((s4+2) & 15) << 3))] = nb[2];
            kT[(s4+3) * 256 + (c ^ (((s4+3) & 15) << 3))] = nb[3];
        }
        __syncthreads();
        // ---- issue next subtile's loads (hide under compute) ----
        if (ss < NSUB - 1) {
            #pragma unroll
            for (int p = 0; p < 8; ++p)
                f4[p] = *(const float4*)(fptr + (ss + 1) * SS + (size_t)p * 32 * 4096);
        }
        const int sw = sw_base + ss * SS;
        // ---- S-GEMM: wave w owns t rows [t0, t0+16), all 32 s ----
        #pragma unroll
        for (int nt = 0; nt < 2; ++nt) {
            f32x4 d; d[0]=0.f; d[1]=0.f; d[2]=0.f; d[3]=0.f;
            #pragma unroll
            for (int kk = 0; kk < 8; ++kk) {
                const int cc = kk * 32 + g * 8;
                const bf16x8 bfr = *(bf16x8*)&kT[(nt * 16 + l15) * 256 + (cc ^ (l15 << 3))];
                d = __builtin_amdgcn_mfma_f32_16x16x32_bf16(afr[kk], bfr, d, 0, 0, 0);
            }
            #pragma unroll
            for (int r = 0; r < 4; ++r) {
                const int t = t0 + g * 4 + r;
                const float sv = d[r] * 0.0625f;
                attn_g[((size_t)bh * 64 + t) * 4096 + sw + nt * 16 + l15] = sv;
                const float p = __expf(sv);
                zp[r] += p;
                P[t * KNW + nt * 16 + l15] = (__bf16)p;
            }
        }
        // ---- AV-GEMM: wave-local (own 16 t rows, all 256 c), K = 32 s ----
        const bf16x8 pa = *(bf16x8*)&P[(t0 + l15) * KNW + g * 8];
        #pragma unroll
        for (int ct = 0; ct < 16; ++ct) {
            const bf16x8 kb = *(bf16x8*)&knat[(ct * 16 + l15) * KNW + g * 8];
            acc[ct] = __builtin_amdgcn_mfma_f32_16x16x32_bf16(pa, kb, acc[ct], 0, 0, 0);
        }
    }

    // ---- epilogue: write AV partials + z partials ----
    const size_t pbase = (size_t)(bh * NC + nc) * 64 * 256;
    #pragma unroll
    for (int ct = 0; ct < 16; ++ct)
        #pragma unroll
        for (int r = 0; r < 4; ++r)
            part[pbase + (size_t)(t0 + g * 4 + r) * 256 + ct * 16 + l15] = acc[ct][r];
    #pragma unroll
    for (int r = 0; r < 4; ++r) {
        float z = zp[r];
        z += __shfl_xor(z, 1); z += __shfl_xor(z, 2);
        z += __shfl_xor(z, 4); z += __shfl_xor(z, 8);
        if (l15 == 0) zbuf[(size_t)(bh * NC + nc) * 64 + t0 + g * 4 + r] = z;
    }
}

// ---------------- K3: combine partials, proj, residual, LayerNorm ----------------
// grid 512: t = bid>>3, 4 consecutive b per block; proj_w row reused x4
__global__ __launch_bounds__(128) void k_post(
    const float* __restrict__ tokens, const float* __restrict__ proj_w,
    const float* __restrict__ proj_b, const float* __restrict__ ln_w,
    const float* __restrict__ ln_b, const float* __restrict__ part,
    const float* __restrict__ zbuf, float* __restrict__ out_tok)
{
    const int t = blockIdx.x >> 3;
    const int b0 = (blockIdx.x & 7) * 4;
    const int d = threadIdx.x;
    __shared__ float av[4][512];
    __shared__ float Zs[4][2];
    __shared__ float red[2][4][2];

    #pragma unroll
    for (int bb = 0; bb < 4; ++bb) {
        const int b = b0 + bb;
        #pragma unroll
        for (int i = 0; i < 4; ++i) {
            const int c = d + 128 * i;
            const int bh = b * 2 + (c >> 8), cc = c & 255;
            float s = 0.f;
            #pragma unroll
            for (int nc = 0; nc < NC; ++nc)
                s += part[((size_t)(bh * NC + nc) * 64 + t) * 256 + cc];
            av[bb][c] = s;
        }
    }
    if (d < 8) {
        const int bb = d >> 1, hh = d & 1;
        const int bh = (b0 + bb) * 2 + hh;
        float z = 0.f;
        for (int nc = 0; nc < NC; ++nc) z += zbuf[(size_t)(bh * NC + nc) * 64 + t];
        Zs[bb][hh] = z;
    }
    __syncthreads();
    #pragma unroll
    for (int bb = 0; bb < 4; ++bb) {
        const float rz0 = 1.f / Zs[bb][0], rz1 = 1.f / Zs[bb][1];
        #pragma unroll
        for (int i = 0; i < 4; ++i) {
            const int c = d + 128 * i;
            av[bb][c] *= (c < 256) ? rz0 : rz1;
        }
    }
    __syncthreads();

    const float pb = proj_b[d];
    float acc4[4] = {pb, pb, pb, pb};
    const float* wr = proj_w + (size_t)d * 512;
    #pragma unroll 4
    for (int k = 0; k < 512; k += 4) {
        const float4 w4 = *(const float4*)(wr + k);
        #pragma unroll
        for (int bb = 0; bb < 4; ++bb) {
            const float4 a4 = *(const float4*)&av[bb][k];
            acc4[bb] += a4.x * w4.x + a4.y * w4.y + a4.z * w4.z + a4.w * w4.w;
        }
    }
    float r[4], s1[4], s2[4];
    #pragma unroll
    for (int bb = 0; bb < 4; ++bb) {
        r[bb] = tokens[((size_t)t * 32 + b0 + bb) * 128 + d] + acc4[bb];
        s1[bb] = r[bb]; s2[bb] = r[bb] * r[bb];
    }
    #pragma unroll
    for (int o = 1; o < 64; o <<= 1)
        #pragma unroll
        for (int bb = 0; bb < 4; ++bb) {
            s1[bb] += __shfl_xor(s1[bb], o);
            s2[bb] += __shfl_xor(s2[bb], o);
        }
    const int wv = d >> 6;
    if ((d & 63) == 0)
        #pragma unroll
        for (int bb = 0; bb < 4; ++bb) { red[0][bb][wv] = s1[bb]; red[1][bb][wv] = s2[bb]; }
    __syncthreads();
    #pragma unroll
    for (int bb = 0; bb < 4; ++bb) {
        const float mean = (red[0][bb][0] + red[0][bb][1]) * (1.f / 128.f);
        const float ex2  = (red[1][bb][0] + red[1][bb][1]) * (1.f / 128.f);
        const float var = ex2 - mean * mean;
        out_tok[((size_t)t * 32 + b0 + bb) * 128 + d] =
            (r[bb] - mean) * rsqrtf(var + 1e-5f) * ln_w[d] + ln_b[d];
    }
}

extern "C" void kernel_launch(void* const* d_in, const int* in_sizes, int n_in,
                              void* d_out, int out_size, void* d_ws, size_t ws_size,
                              hipStream_t stream) {
    const float* features = (const float*)d_in[0];
    const float* tokens   = (const float*)d_in[1];
    const float* q_w      = (const float*)d_in[2];
    const float* q_b      = (const float*)d_in[3];
    const float* proj_w   = (const float*)d_in[4];
    const float* proj_b   = (const float*)d_in[5];
    const float* ln_w     = (const float*)d_in[6];
    const float* ln_b     = (const float*)d_in[7];

    float* out = (float*)d_out;
    float* out_attn = out + (size_t)64 * 32 * 128;       // tok first, then attn

    __bf16* ws_q = (__bf16*)d_ws;                        // 2 MB
    float* part = (float*)((char*)d_ws + (size_t)2 * 1024 * 1024);   // 33.6 MB
    float* zbuf = part + (size_t)64 * NC * 64 * 256;     // 128 KB

    k_qproj<<<512, 128, 0, stream>>>(tokens, q_w, q_b, ws_q);
    k_attn<<<64 * NC, 256, 0, stream>>>(features, ws_q, out_attn, part, zbuf);
    k_post<<<512, 128, 0, stream>>>(tokens, proj_w, proj_b, ln_w, ln_b, part, zbuf, out);
}